// Round 13
// baseline (547.084 us; speedup 1.0000x reference)
//
#include <hip/hip_runtime.h>
#include <hip/hip_bf16.h>

#define NTOK   8192
#define DMODEL 1024
#define NEXP   8
#define HFFN   4096
#define NSLOT  16384
#define MAXWL  136

typedef __bf16 bf16x8 __attribute__((ext_vector_type(8)));
typedef float  f32x4  __attribute__((ext_vector_type(4)));
typedef unsigned short u16;
typedef u16 u16x8 __attribute__((ext_vector_type(8)));

typedef const __attribute__((address_space(1))) void* gas_ptr;
typedef __attribute__((address_space(3))) void* las_ptr;

__device__ inline u16 f2b(float f) {
  __hip_bfloat16 h = __float2bfloat16(f);
  return *reinterpret_cast<u16*>(&h);
}

// ---- router: one wave per token; emits bf16 x; fused expert-count histogram ----
__global__ void router_k(const float* __restrict__ x, const float* __restrict__ rw,
                         const float* __restrict__ rb, int* __restrict__ tok_e,
                         float* __restrict__ tok_g, int* __restrict__ counts,
                         u16* __restrict__ xb) {
  __shared__ int h[NEXP];
  int tid = threadIdx.x;
  if (tid < NEXP) h[tid] = 0;
  __syncthreads();
  int wave = tid >> 6, lane = tid & 63;
  int t = blockIdx.x * 4 + wave;
  const float* xr = x + (size_t)t * DMODEL;
  float acc[NEXP];
#pragma unroll
  for (int e = 0; e < NEXP; e++) acc[e] = 0.f;
#pragma unroll
  for (int i = 0; i < 4; i++) {
    int d = i * 256 + lane * 4;
    float4 xv = *(const float4*)(xr + d);
    ushort4 o;
    o.x = f2b(xv.x); o.y = f2b(xv.y); o.z = f2b(xv.z); o.w = f2b(xv.w);
    *(ushort4*)(xb + (size_t)t * DMODEL + d) = o;
#pragma unroll
    for (int e = 0; e < NEXP; e++) {
      float4 wv = *(const float4*)(rw + (size_t)e * DMODEL + d);
      acc[e] += xv.x * wv.x + xv.y * wv.y + xv.z * wv.z + xv.w * wv.w;
    }
  }
#pragma unroll
  for (int e = 0; e < NEXP; e++) {
#pragma unroll
    for (int off = 32; off > 0; off >>= 1) acc[e] += __shfl_xor(acc[e], off);
  }
  if (lane == 0) {
    float lg[NEXP];
#pragma unroll
    for (int e = 0; e < NEXP; e++) lg[e] = acc[e] + rb[e];
    int e0 = 0;
#pragma unroll
    for (int e = 1; e < NEXP; e++) if (lg[e] > lg[e0]) e0 = e;
    int e1 = (e0 == 0) ? 1 : 0;
#pragma unroll
    for (int e = 0; e < NEXP; e++) if (e != e0 && lg[e] > lg[e1]) e1 = e;
    float ex = expf(lg[e1] - lg[e0]);       // <= 1
    float g0 = 1.f / (1.f + ex);
    float g1 = ex / (1.f + ex);
    tok_e[2 * t]     = e0;  tok_e[2 * t + 1] = e1;
    tok_g[2 * t]     = g0;  tok_g[2 * t + 1] = g1;
    atomicAdd(&h[e0], 1);
    atomicAdd(&h[e1], 1);
  }
  __syncthreads();
  if (tid < NEXP && h[tid]) atomicAdd(&counts[tid], h[tid]);
}

// ---------------- offsets + 128-grain tile worklist ----------------
__global__ void offsets_k(const int* __restrict__ counts, int* __restrict__ offsets,
                          int* __restrict__ wl) {
  if (threadIdx.x == 0) {
    int s = 0;
    for (int e = 0; e < NEXP; e++) { offsets[e] = s; s += counts[e]; }
    offsets[NEXP] = s;
    int n = 0;
    for (int e = 0; e < NEXP; e++)
      for (int t = 0; t * 128 < counts[e]; ++t) wl[n++] = (e << 16) | t;
    for (int i = n; i < MAXWL; ++i) wl[i] = -1;
  }
}

// ---- assign: slot -> token map + per-slot gate weight ----
__global__ void assign_k(const int* __restrict__ tok_e, const float* __restrict__ tok_g,
                         int* __restrict__ cursors, const int* __restrict__ offsets,
                         int* __restrict__ row_tok, float* __restrict__ slot_g) {
  __shared__ int h[NEXP], base[NEXP];
  int tid = threadIdx.x;
  if (tid < NEXP) h[tid] = 0;
  __syncthreads();
  int t = blockIdx.x * 256 + tid;
  int e0 = tok_e[2 * t], e1 = tok_e[2 * t + 1];
  int r0 = atomicAdd(&h[e0], 1);
  int r1 = atomicAdd(&h[e1], 1);
  __syncthreads();
  if (tid < NEXP) base[tid] = atomicAdd(&cursors[tid], h[tid]);
  __syncthreads();
  int s0 = offsets[e0] + base[e0] + r0;
  int s1 = offsets[e1] + base[e1] + r1;
  row_tok[s0] = t;  slot_g[s0] = tok_g[2 * t];
  row_tok[s1] = t;  slot_g[s1] = tok_g[2 * t + 1];
}

// ---------------- weight transpose + bf16: src[e][R][C] f32 -> dst[e][C][R] bf16 ----
__global__ void wtrans_k(const float* __restrict__ src, u16* __restrict__ dst,
                         int R, int C) {
  __shared__ u16 tile[64][72];
  int e = blockIdx.z;
  int r0 = blockIdx.x * 64, c0 = blockIdx.y * 64;
  int tid = threadIdx.x;
  int tr = tid >> 2, tc = (tid & 3) * 16;
  const float* sp = src + (size_t)e * R * C + (size_t)(r0 + tr) * C + c0 + tc;
#pragma unroll
  for (int i = 0; i < 16; i += 4) {
    float4 v = *(const float4*)(sp + i);
    tile[tr][tc + i]     = f2b(v.x);
    tile[tr][tc + i + 1] = f2b(v.y);
    tile[tr][tc + i + 2] = f2b(v.z);
    tile[tr][tc + i + 3] = f2b(v.w);
  }
  __syncthreads();
  u16* dbase = dst + (size_t)e * R * C;
#pragma unroll
  for (int it = 0; it < 2; ++it) {
    int oc  = it * 32 + (tid >> 3);
    int seg = (tid & 7) * 8;
    u16x8 o;
#pragma unroll
    for (int j = 0; j < 8; ++j) o[j] = tile[seg + j][oc];
    *(u16x8*)(dbase + (size_t)(c0 + oc) * R + r0 + seg) = o;
  }
}

// ---------------- MFMA GEMM: 128x128 tile, 4 waves, BK=32, 2-deep counted --------
// Core identical to R12 (proven). New: GATHER (A rows via srow token map) and
// ATOMIC epilogue (out[tok][col] += g*(acc + b2[col] on kq==0) via f32 atomics —
// merges split-K partials and the MoE combine for free).
template <int KTOT, int KCHUNK, int NTOT, int NY, bool RELU, bool GATHER, bool ATOMIC>
__global__ __launch_bounds__(256, 4) void moe_gemm_k(
    const u16* __restrict__ A, const u16* __restrict__ Bt,
    const float* __restrict__ bias, u16* __restrict__ Out, float* __restrict__ fout,
    const int* __restrict__ counts, const int* __restrict__ offsets,
    const int* __restrict__ wl, const int* __restrict__ row_tok,
    const float* __restrict__ slot_g) {
  __shared__ __align__(16) u16 Als[2 * 128 * 32];   // 2 bufs x [128][32] = 16KB
  __shared__ __align__(16) u16 Bls[2 * 128 * 32];
  __shared__ int srow[128];

  int nwg = gridDim.x;                              // MAXWL*NY*NKQ, %8==0
  int lid = blockIdx.x;
  int orig = (lid & 7) * (nwg >> 3) + (lid >> 3);   // XCD-chunked swizzle
  int kq   = orig / (MAXWL * NY);
  int r1   = orig - kq * (MAXWL * NY);
  int xp   = r1 / (NY * 2);                         // xt-pair id
  int r2   = r1 - xp * (NY * 2);
  int xt = (xp << 1) | (r2 & 1);
  int y  = r2 >> 1;
  int w = wl[xt];
  if (w < 0) return;
  int e   = w >> 16;
  int tr0 = (w & 0xffff) << 7;
  int cnt = counts[e];
  int seg = offsets[e];
  int n0  = y << 7;

  int tid = threadIdx.x;
  if (GATHER) {
    if (tid < 128) {
      int idx = tr0 + tid;
      if (idx > cnt - 1) idx = cnt - 1;
      srow[tid] = row_tok[seg + idx];
    }
    __syncthreads();
  }

  int wid = tid >> 6, lane = tid & 63;
  int wm = wid >> 1, wn = wid & 1;
  int l15 = lane & 15, lhi = lane >> 4;

  // staging: thread -> (row = tid>>2 [+64], chunk = tid&3), source pre-swizzled
  int co = (((tid & 3) ^ ((tid >> 3) & 3)) << 3) + kq * KCHUNK;
  int ar0 = tid >> 2, ar1 = 64 + (tid >> 2);
  const u16* gA0 = A + (size_t)(GATHER ? srow[ar0] : (seg + tr0 + ar0)) * KTOT + co;
  const u16* gA1 = A + (size_t)(GATHER ? srow[ar1] : (seg + tr0 + ar1)) * KTOT + co;
  const u16* Bte = Bt + (size_t)e * NTOT * KTOT;
  const u16* gB0 = Bte + (size_t)(n0 + (tid >> 2)) * KTOT + co;
  const u16* gB1 = gB0 + (size_t)64 * KTOT;
  char* Ab = (char*)Als;
  char* Bb = (char*)Bls;
  int sdst = wid << 10;   // wave-uniform 1KB slice within each 4KB half

  auto stage = [&](int bs, int kb) {
    __builtin_amdgcn_global_load_lds((gas_ptr)(gA0 + kb), (las_ptr)(Ab + bs * 8192 + sdst), 16, 0, 0);
    __builtin_amdgcn_global_load_lds((gas_ptr)(gA1 + kb), (las_ptr)(Ab + bs * 8192 + 4096 + sdst), 16, 0, 0);
    __builtin_amdgcn_global_load_lds((gas_ptr)(gB0 + kb), (las_ptr)(Bb + bs * 8192 + sdst), 16, 0, 0);
    __builtin_amdgcn_global_load_lds((gas_ptr)(gB1 + kb), (las_ptr)(Bb + bs * 8192 + 4096 + sdst), 16, 0, 0);
  };

  // fragment read offsets (bytes): row*64 + (chunk ^ ((row>>1)&3))*16
  int xsw = ((lhi ^ ((l15 >> 1) & 3)) << 4);
  int aoff = (wm * 64 + l15) * 64 + xsw;
  int boff = (wn * 64 + l15) * 64 + xsw;

  f32x4 acc[4][4] = {};
  constexpr int NT = KCHUNK / 32;

  stage(0, 0);                       // prologue: tile 0 in flight
  for (int kt = 0; kt < NT; ++kt) {
    int cur = kt & 1;
    if (kt + 1 < NT) {
      stage(cur ^ 1, (kt + 1) * 32);                    // tile T+1 issued early
      asm volatile("s_waitcnt vmcnt(4)" ::: "memory");  // tile T landed; T+1 in flight
    } else {
      asm volatile("s_waitcnt vmcnt(0)" ::: "memory");
    }
    __builtin_amdgcn_s_barrier();        // publish buf cur
    __builtin_amdgcn_sched_barrier(0);

    const char* ab = Ab + cur * 8192;
    const char* bb = Bb + cur * 8192;
    bf16x8 af[4], bv[4];
#pragma unroll
    for (int m = 0; m < 4; ++m) af[m] = *(const bf16x8*)(ab + aoff + m * 1024);
#pragma unroll
    for (int n = 0; n < 4; ++n) bv[n] = *(const bf16x8*)(bb + boff + n * 1024);
#pragma unroll
    for (int m = 0; m < 4; ++m)
#pragma unroll
      for (int n = 0; n < 4; ++n)
        acc[m][n] = __builtin_amdgcn_mfma_f32_16x16x32_bf16(af[m], bv[n], acc[m][n], 0, 0, 0);
    __builtin_amdgcn_s_barrier();        // readers done before T+2 overwrites cur
  }

  // epilogue: C/D layout col=lane&15, row=(lane>>4)*4+reg
  int cb = n0 + wn * 64 + l15;
  int rb0 = tr0 + wm * 64 + lhi * 4;
  if (ATOMIC) {
    const float* b2e = bias + (size_t)e * NTOT;
    float bs4[4];
#pragma unroll
    for (int n = 0; n < 4; ++n) bs4[n] = (kq == 0) ? b2e[cb + n * 16] : 0.f;
#pragma unroll
    for (int m = 0; m < 4; ++m) {
#pragma unroll
      for (int r = 0; r < 4; ++r) {
        int gi = rb0 + m * 16 + r;
        if (gi >= cnt) continue;
        int tok = row_tok[seg + gi];
        float g = slot_g[seg + gi];
        float* orow = fout + (size_t)tok * NTOT + cb;
#pragma unroll
        for (int n = 0; n < 4; ++n)
          atomicAdd(&orow[n * 16], (acc[m][n][r] + bs4[n]) * g);
      }
    }
  } else {
    const float* bias_e = bias + (size_t)e * NTOT;
    float bs4[4];
#pragma unroll
    for (int n = 0; n < 4; ++n) bs4[n] = bias_e[cb + n * 16];
#pragma unroll
    for (int m = 0; m < 4; ++m) {
#pragma unroll
      for (int r = 0; r < 4; ++r) {
        int gi = rb0 + m * 16 + r;
        if (gi >= cnt) continue;
        size_t orow = (size_t)(seg + gi) * NTOT + cb;
#pragma unroll
        for (int n = 0; n < 4; ++n) {
          float v = acc[m][n][r] + bs4[n];
          if (RELU) v = fmaxf(v, 0.f);
          Out[orow + n * 16] = f2b(v);
        }
      }
    }
  }
}

extern "C" void kernel_launch(void* const* d_in, const int* in_sizes, int n_in,
                              void* d_out, int out_size, void* d_ws, size_t ws_size,
                              hipStream_t stream) {
  const float* x  = (const float*)d_in[0];
  const float* rw = (const float*)d_in[1];
  const float* rb = (const float*)d_in[2];
  const float* w1 = (const float*)d_in[3];
  const float* b1 = (const float*)d_in[4];
  const float* w2 = (const float*)d_in[5];
  const float* b2 = (const float*)d_in[6];

  char* ws = (char*)d_ws;
  size_t o = 0;
  u16* w1t = (u16*)(ws + o); o += (size_t)NEXP * HFFN * DMODEL * 2;       // 64 MiB
  u16* w2t = (u16*)(ws + o); o += (size_t)NEXP * HFFN * DMODEL * 2;       // 64 MiB
  u16* xb  = (u16*)(ws + o); o += (size_t)NTOK * DMODEL * 2;              // 16 MiB
  u16* hc  = (u16*)(ws + o); o += (size_t)(NSLOT + 256) * HFFN * 2;       // 136 MiB
  int*   tok_e   = (int*)(ws + o);   o += NTOK * 2 * sizeof(int);
  float* tok_g   = (float*)(ws + o); o += NTOK * 2 * sizeof(float);
  int*   row_tok = (int*)(ws + o);   o += NSLOT * sizeof(int);
  float* slot_g  = (float*)(ws + o); o += NSLOT * sizeof(float);
  int*   meta    = (int*)(ws + o);   o += 32 * sizeof(int);
  int*   wl      = (int*)(ws + o);   o += MAXWL * sizeof(int);
  int* counts  = meta;
  int* cursors = meta + 8;
  int* offsets = meta + 16;

  hipMemsetAsync(meta, 0, 64, stream);
  hipMemsetAsync(d_out, 0, (size_t)NTOK * DMODEL * sizeof(float), stream);
  router_k<<<NTOK / 4, 256, 0, stream>>>(x, rw, rb, tok_e, tok_g, counts, xb);
  offsets_k<<<1, 64, 0, stream>>>(counts, offsets, wl);
  assign_k<<<NTOK / 256, 256, 0, stream>>>(tok_e, tok_g, cursors, offsets, row_tok, slot_g);
  wtrans_k<<<dim3(DMODEL / 64, HFFN / 64, NEXP), 256, 0, stream>>>(w1, w1t, DMODEL, HFFN);
  wtrans_k<<<dim3(HFFN / 64, DMODEL / 64, NEXP), 256, 0, stream>>>(w2, w2t, HFFN, DMODEL);

  // GEMM1: gather(xb by srow) @ w1t^T -> hc [slots,4096], bias+relu, bf16
  moe_gemm_k<DMODEL, DMODEL, HFFN, HFFN / 128, true, true, false>
      <<<MAXWL * (HFFN / 128), 256, 0, stream>>>(
          xb, w1t, b1, hc, nullptr, counts, offsets, wl, row_tok, slot_g);
  // GEMM2 (split-K=2): hc @ w2t^T -> atomic out[tok] += g*(y + b2) (kq0 adds bias)
  moe_gemm_k<HFFN, HFFN / 2, DMODEL, DMODEL / 128, false, false, true>
      <<<MAXWL * (DMODEL / 128) * 2, 256, 0, stream>>>(
          hc, w2t, b2, nullptr, (float*)d_out, counts, offsets, wl, row_tok, slot_g);
}